// Round 3
// baseline (659.368 us; speedup 1.0000x reference)
//
#include <hip/hip_runtime.h>
#include <math.h>

#define NB 16
#define NC 48
#define NT 96
#define NP 12
#define NFF 64
#define CT 4608          // NC*NT
#define STEPS 7
#define NBLK 576         // 3 blocks per (b,p); must be <= 3 blocks/CU * 256
#define NTHR 192

// ---- exact-GELU via Abramowitz-Stegun 7.1.26 erf (|abs err| <= 1.5e-7) ----
__device__ __forceinline__ float erf_fast(float x) {
    float a = fabsf(x);
    float t = __builtin_amdgcn_rcpf(fmaf(0.3275911f, a, 1.0f));
    float p = t * fmaf(t, fmaf(t, fmaf(t, fmaf(t, 1.061405429f, -1.453152027f),
                                       1.421413741f), -0.284496736f), 0.254829592f);
    float E = __builtin_amdgcn_exp2f(-a * a * 1.4426950408889634f);
    float y = fmaf(-p, E, 1.0f);
    return copysignf(y, x);
}
__device__ __forceinline__ float gelu_exact(float u) {
    float e  = erf_fast(u * 0.70710678118654752f);
    float hu = 0.5f * u;
    return fmaf(hu, e, hu);
}

// ---- manual grid barrier: generation counter, device(agent)-scope atomics --
// flags zeroed by hipMemsetAsync before every launch. All NBLK blocks are
// co-resident by construction (see launch_bounds/LDS math above), so spinning
// is deadlock-free.
__device__ __forceinline__ void grid_barrier(unsigned* cnt, unsigned* gen) {
    __syncthreads();   // compiler drains all this block's vmem before s_barrier
    if (threadIdx.x == 0) {
        __threadfence();   // make this block's global writes visible device-wide
        unsigned g = __hip_atomic_load(gen, __ATOMIC_RELAXED, __HIP_MEMORY_SCOPE_AGENT);
        unsigned old = __hip_atomic_fetch_add(cnt, 1u, __ATOMIC_ACQ_REL, __HIP_MEMORY_SCOPE_AGENT);
        if (old == NBLK - 1u) {
            __hip_atomic_store(cnt, 0u, __ATOMIC_RELAXED, __HIP_MEMORY_SCOPE_AGENT);
            __hip_atomic_fetch_add(gen, 1u, __ATOMIC_RELEASE, __HIP_MEMORY_SCOPE_AGENT);
        } else {
            while (__hip_atomic_load(gen, __ATOMIC_RELAXED, __HIP_MEMORY_SCOPE_AGENT) == g)
                __builtin_amdgcn_s_sleep(2);
        }
        __threadfence();   // acquire side: invalidate stale cached lines
    }
    __syncthreads();
}

__global__ __launch_bounds__(NTHR, 3) void fused_kernel(
    const float* __restrict__ x,
    const float* __restrict__ g0, const float* __restrict__ b0,
    const float* __restrict__ g1, const float* __restrict__ b1,
    const float* __restrict__ g2, const float* __restrict__ b2,
    const float* __restrict__ Wagg, const float* __restrict__ bagg,
    const float* __restrict__ W1, const float* __restrict__ bm1,
    const float* __restrict__ W2, const float* __restrict__ wmsg,
    const float* __restrict__ bmsg,
    float* __restrict__ out, float* __restrict__ xn, unsigned* __restrict__ bar)
{
    const int blk = blockIdx.x, tid = threadIdx.x;

    __shared__ float prev_sh[NB * NC * NP];   // 9216 f = 36 KB : prev patch
    __shared__ float Aw[NC * NP];             // alpha(c,p') * Wagg[p][p']
    __shared__ float bw[NC * NP];             // beta(c,p')  * Wagg[p][p']
    __shared__ float bconst[NC];
    __shared__ float res_sh[NB * NC];         // res[b'][c] at our p
    __shared__ float tv[NC];                  // t[b][p][c]
    __shared__ float erow[16][49];
    __shared__ float rowm1[16], rowm3[16];
    __shared__ float red[16][2];
    __shared__ float4 coef[NFF];
    __shared__ float wgs[NP];                 // Wagg row for our p

    const int bp = blk / 3;                   // (b,p) pair
    const int i0 = (blk % 3) * 16;            // this block's 16 output rows
    const int b = bp / NP, p = bp % NP;

    if (tid < NFF)
        coef[tid] = make_float4(W1[2 * tid], W1[2 * tid + 1], bm1[tid], W2[tid]);
    if (tid < NP) wgs[tid] = Wagg[p * NP + tid];   // einsum 'bcp,qp': W[q=p][p']

    // ---------------- bn0 (blocks 0..23): BN over full x -------------------
    if (blk < CT / NTHR) {
        int f = blk * NTHR + tid;
        float v[NB];
        float s = 0.f;
#pragma unroll
        for (int bb = 0; bb < NB; bb++) { v[bb] = x[bb * CT + f]; s += v[bb]; }
        float mu = s * (1.f / NB);
        float var = 0.f;
#pragma unroll
        for (int bb = 0; bb < NB; bb++) { float d = v[bb] - mu; var = fmaf(d, d, var); }
        var *= (1.f / NB);
        float rs = rsqrtf(var + 1e-5f);
        float g = g0[f], bbv = b0[f];
        int c = f / NT, tt = f % NT;
#pragma unroll
        for (int bb = 0; bb < NB; bb++) {
            float y = (v[bb] - mu) * rs * g + bbv;
            xn[bb * CT + f] = y;
            if (tt < NP) out[(bb * NC + c) * NT + tt] = y;
        }
    }
    grid_barrier(bar, bar + 1);

    const float wm = wmsg[0], bmv = bmsg[0], baggp = bagg[p];

    for (int s = 0; s < STEPS; s++) {
        // ---- stage A: stage prev patch (out cols 12s..12s+12) into LDS ----
#pragma unroll
        for (int it = 0; it < 12; it++) {
            int idx = it * NTHR + tid;            // 2304 float4s
            int row = idx / 3, q = idx - row * 3; // row = b'*48+c
            *(float4*)&prev_sh[idx * 4] =
                *(const float4*)&out[row * NT + NP * s + 4 * q];
        }
        __syncthreads();

        // ---- stage B: BN1 stats per feature f=(c,p'); fold into Aw/bw -----
#pragma unroll
        for (int u = 0; u < 3; u++) {
            int f = tid + NTHR * u;               // 0..575
            float sum = 0.f;
#pragma unroll
            for (int bb = 0; bb < NB; bb++) sum += prev_sh[bb * 576 + f];
            float mu = sum * (1.f / NB);
            float var = 0.f;
#pragma unroll
            for (int bb = 0; bb < NB; bb++) {
                float d = prev_sh[bb * 576 + f] - mu; var = fmaf(d, d, var);
            }
            var *= (1.f / NB);
            float rs = rsqrtf(var + 1e-5f);
            float alpha = g1[f] * rs;
            float beta  = fmaf(-mu, alpha, b1[f]);
            float w = wgs[f % NP];
            Aw[f] = alpha * w;
            bw[f] = beta * w;
        }
        __syncthreads();
        if (tid < NC) {
            float acc = baggp;
#pragma unroll
            for (int q = 0; q < NP; q++) acc += bw[tid * NP + q];
            bconst[tid] = acc;
        }
        __syncthreads();

        // ---- stage C: agg(q=p) + gelu + xw -> res_sh ----------------------
#pragma unroll
        for (int u = 0; u < 4; u++) {
            int o = tid + NTHR * u;               // 0..767 = b'*48+c
            int c = o % NC;
            float acc = bconst[c];
            const float4* pv = (const float4*)&prev_sh[o * NP];
            const float4* aw = (const float4*)&Aw[c * NP];
#pragma unroll
            for (int q = 0; q < 3; q++) {
                float4 a4 = pv[q], w4 = aw[q];
                acc = fmaf(a4.x, w4.x, acc); acc = fmaf(a4.y, w4.y, acc);
                acc = fmaf(a4.z, w4.z, acc); acc = fmaf(a4.w, w4.w, acc);
            }
            res_sh[o] = gelu_exact(acc) + xn[o * NT + NP + NP * s + p];
        }
        __syncthreads();

        // ---- stage D: BN2 over b' ; t vector for our b --------------------
        if (tid < 32) ((float*)red)[tid] = 0.f;
        if (tid < NC) {
            int c = tid;
            float sum = 0.f;
#pragma unroll
            for (int bb = 0; bb < NB; bb++) sum += res_sh[bb * NC + c];
            float mu = sum * (1.f / NB);
            float var = 0.f;
#pragma unroll
            for (int bb = 0; bb < NB; bb++) {
                float d = res_sh[bb * NC + c] - mu; var = fmaf(d, d, var);
            }
            var *= (1.f / NB);
            float rs = rsqrtf(var + 1e-5f);
            tv[c] = (res_sh[b * NC + c] - mu) * rs * g2[c * NP + p] + b2[c * NP + p];
        }
        __syncthreads();

        // ---- stage E: edge MLP + top-3 + softmax + message ----------------
        {
            int j = tid % NC, rg = tid / NC;      // rg in 0..3
            float zj = tv[j];
            float zi[4], e[4];
#pragma unroll
            for (int k = 0; k < 4; k++) { zi[k] = tv[i0 + rg + 4 * k]; e[k] = 0.f; }

#pragma unroll 4
            for (int f = 0; f < NFF; f++) {
                float4 cf = coef[f];
                float base = fmaf(cf.y, zj, cf.z);
#pragma unroll
                for (int k = 0; k < 4; k++) {
                    float u = fmaf(cf.x, zi[k], base);
                    e[k] = fmaf(gelu_exact(u), cf.w, e[k]);
                }
            }
#pragma unroll
            for (int k = 0; k < 4; k++) erow[rg + 4 * k][j] = e[k];
            __syncthreads();

            if (tid < 16) {
                float m1 = -1e30f, m2 = -1e30f, m3 = -1e30f;
#pragma unroll 8
                for (int k = 0; k < NC; k++) {
                    float v = erow[tid][k];
                    float n1 = fmaxf(m1, v), r1 = fminf(m1, v);
                    float n2 = fmaxf(m2, r1), r2 = fminf(m2, r1);
                    float n3 = fmaxf(m3, r2);
                    m1 = n1; m2 = n2; m3 = n3;
                }
                rowm1[tid] = m1; rowm3[tid] = m3;
            }
            __syncthreads();

            float msg = fmaf(zj, wm, bmv);
#pragma unroll
            for (int k = 0; k < 4; k++) {
                int r = rg + 4 * k;
                float ek = e[k];
                if (ek >= rowm3[r]) {             // ~3 lanes per row
                    int rank = 0;
                    for (int kk = 0; kk < NC; kk++) {
                        float v = erow[r][kk];
                        rank += (v > ek) || (v == ek && kk < j);
                    }
                    if (rank < 3) {               // exact jax top_k tie-break
                        float w = __builtin_amdgcn_exp2f((ek - rowm1[r]) * 1.4426950408889634f);
                        atomicAdd(&red[r][0], w);
                        atomicAdd(&red[r][1], w * msg);
                    }
                }
            }
            __syncthreads();

            if (tid < 16) {
                int i = i0 + tid;
                float znew = red[tid][1] / red[tid][0];
                out[(b * NC + i) * NT + NP * (s + 1) + p] =
                    res_sh[b * NC + i] + 0.5f * znew;      // ALPHA = 0.5
            }
        }
        if (s < STEPS - 1) grid_barrier(bar, bar + 1);
    }
}

extern "C" void kernel_launch(void* const* d_in, const int* in_sizes, int n_in,
                              void* d_out, int out_size, void* d_ws, size_t ws_size,
                              hipStream_t stream)
{
    const float* x    = (const float*)d_in[0];
    const float* g0   = (const float*)d_in[1];
    const float* b0   = (const float*)d_in[2];
    const float* g1   = (const float*)d_in[3];
    const float* b1   = (const float*)d_in[4];
    const float* g2   = (const float*)d_in[5];
    const float* b2   = (const float*)d_in[6];
    const float* Wagg = (const float*)d_in[7];
    const float* bagg = (const float*)d_in[8];
    const float* W1   = (const float*)d_in[9];
    const float* bm1  = (const float*)d_in[10];
    const float* W2   = (const float*)d_in[11];
    // d_in[12] = bm2: uniform shift of e -> invariant under top-k & softmax
    const float* wmsg = (const float*)d_in[13];
    const float* bmsg = (const float*)d_in[14];
    float* out = (float*)d_out;

    float* xn = (float*)d_ws;                              // 73728 floats
    unsigned* bar = (unsigned*)((char*)d_ws + 73728 * 4);  // barrier flags

    hipMemsetAsync(bar, 0, 256, stream);   // zero barrier flags (capturable)
    fused_kernel<<<NBLK, NTHR, 0, stream>>>(x, g0, b0, g1, b1, g2, b2, Wagg,
                                            bagg, W1, bm1, W2, wmsg, bmsg,
                                            out, xn, bar);
}

// Round 4
// 394.756 us; speedup vs baseline: 1.6703x; 1.6703x over previous
//
#include <hip/hip_runtime.h>
#include <math.h>

#define NB 16
#define NC 48
#define NT 96
#define NP 12
#define NFF 64
#define CT 4608          // NC*NT
#define STEPS 7
#define NBLK 576         // 3 blocks per (b,p); 3 blocks/CU * 256 CU >= 576 -> co-resident
#define NTHR 192

// ---- exact-GELU via Abramowitz-Stegun 7.1.26 erf (|abs err| <= 1.5e-7) ----
__device__ __forceinline__ float erf_fast(float x) {
    float a = fabsf(x);
    float t = __builtin_amdgcn_rcpf(fmaf(0.3275911f, a, 1.0f));
    float p = t * fmaf(t, fmaf(t, fmaf(t, fmaf(t, 1.061405429f, -1.453152027f),
                                       1.421413741f), -0.284496736f), 0.254829592f);
    float E = __builtin_amdgcn_exp2f(-a * a * 1.4426950408889634f);
    float y = fmaf(-p, E, 1.0f);
    return copysignf(y, x);
}
__device__ __forceinline__ float gelu_exact(float u) {
    float e  = erf_fast(u * 0.70710678118654752f);
    float hu = 0.5f * u;
    return fmaf(hu, e, hu);
}

// ---- LLC-coherent (cross-XCD) data path: sc0 sc1 bypasses the non-coherent
// per-XCD L2, so NO buffer_wbl2/buffer_inv fences are ever needed. ----------
__device__ __forceinline__ float4 load_f4_llc(const float* p) {
    float4 v;
    asm volatile("global_load_dwordx4 %0, %1, off sc0 sc1" : "=v"(v) : "v"(p));
    return v;
}
__device__ __forceinline__ void store_f_llc(float* p, float v) {
    asm volatile("global_store_dword %0, %1, off sc0 sc1" :: "v"(p), "v"(v) : "memory");
}
__device__ __forceinline__ void waitcnt0() {
    asm volatile("s_waitcnt vmcnt(0)" ::: "memory");
}

// ---- manual grid barrier: RELAXED agent atomics only (no cache maintenance).
// Ordering: waitcnt0 guarantees this block's sc1 stores reached the LLC before
// the arrival add; gen bump happens after all arrivals -> transitively after
// all data. Spinners' post-barrier sc1 loads read the LLC directly.
__device__ __forceinline__ void grid_barrier(unsigned* cnt, unsigned* gen) {
    __syncthreads();
    if (threadIdx.x == 0) {
        waitcnt0();
        unsigned g = __hip_atomic_load(gen, __ATOMIC_RELAXED, __HIP_MEMORY_SCOPE_AGENT);
        unsigned old = __hip_atomic_fetch_add(cnt, 1u, __ATOMIC_RELAXED, __HIP_MEMORY_SCOPE_AGENT);
        if (old == NBLK - 1u) {
            __hip_atomic_store(cnt, 0u, __ATOMIC_RELAXED, __HIP_MEMORY_SCOPE_AGENT);
            waitcnt0();   // reset visible before release (no next-gen race)
            __hip_atomic_fetch_add(gen, 1u, __ATOMIC_RELAXED, __HIP_MEMORY_SCOPE_AGENT);
        } else {
            while (__hip_atomic_load(gen, __ATOMIC_RELAXED, __HIP_MEMORY_SCOPE_AGENT) == g)
                __builtin_amdgcn_s_sleep(2);
        }
    }
    __syncthreads();
}

__global__ __launch_bounds__(NTHR, 3) void fused_kernel(
    const float* __restrict__ x,
    const float* __restrict__ g0, const float* __restrict__ b0,
    const float* __restrict__ g1, const float* __restrict__ b1,
    const float* __restrict__ g2, const float* __restrict__ b2,
    const float* __restrict__ Wagg, const float* __restrict__ bagg,
    const float* __restrict__ W1, const float* __restrict__ bm1,
    const float* __restrict__ W2, const float* __restrict__ wmsg,
    const float* __restrict__ bmsg,
    float* __restrict__ out, float* __restrict__ xn, unsigned* __restrict__ bar)
{
    const int blk = blockIdx.x, tid = threadIdx.x;

    __shared__ float prev_sh[NB * NC * NP];   // 9216 f = 36 KB : prev patch
    __shared__ float Aw[NC * NP];             // alpha(c,p') * Wagg[p][p']
    __shared__ float bw[NC * NP];             // beta(c,p')  * Wagg[p][p']
    __shared__ float bconst[NC];
    __shared__ float res_sh[NB * NC];         // res[b'][c] at our p
    __shared__ float tv[NC];                  // t[b][p][c]
    __shared__ float erow[16][49];
    __shared__ float rowm1[16], rowm3[16];
    __shared__ float red[16][2];
    __shared__ float4 coef[NFF];
    __shared__ float wgs[NP];                 // Wagg row for our p

    const int bp = blk / 3;                   // (b,p) pair
    const int i0 = (blk % 3) * 16;            // this block's 16 output rows
    const int b = bp / NP, p = bp % NP;

    if (tid < NFF)
        coef[tid] = make_float4(W1[2 * tid], W1[2 * tid + 1], bm1[tid], W2[tid]);
    if (tid < NP) wgs[tid] = Wagg[p * NP + tid];   // einsum 'bcp,qp': W[q=p][p']

    // ---------------- bn0 (blocks 0..23): BN over full x -------------------
    // xn and the 'first' out-patch cross blocks -> write-through to LLC.
    if (blk < CT / NTHR) {
        int f = blk * NTHR + tid;
        float v[NB];
        float s = 0.f;
#pragma unroll
        for (int bb = 0; bb < NB; bb++) { v[bb] = x[bb * CT + f]; s += v[bb]; }
        float mu = s * (1.f / NB);
        float var = 0.f;
#pragma unroll
        for (int bb = 0; bb < NB; bb++) { float d = v[bb] - mu; var = fmaf(d, d, var); }
        var *= (1.f / NB);
        float rs = rsqrtf(var + 1e-5f);
        float g = g0[f], bbv = b0[f];
        int c = f / NT, tt = f % NT;
#pragma unroll
        for (int bb = 0; bb < NB; bb++) {
            float y = (v[bb] - mu) * rs * g + bbv;
            store_f_llc(&xn[bb * CT + f], y);
            if (tt < NP) store_f_llc(&out[(bb * NC + c) * NT + tt], y);
        }
    }
    grid_barrier(bar, bar + 1);

    const float wm = wmsg[0], bmv = bmsg[0], baggp = bagg[p];

    for (int s = 0; s < STEPS; s++) {
        // ---- stage A: stage prev patch (out cols 12s..12s+12) into LDS ----
        // sc1 loads: bypass stale L1/L2 (48-B patches straddle 64-B lines).
        float4 tmp[12];
#pragma unroll
        for (int it = 0; it < 12; it++) {
            int idx = it * NTHR + tid;            // 2304 float4s
            int row = idx / 3, q = idx - row * 3; // row = b'*48+c
            tmp[it] = load_f4_llc(&out[row * NT + NP * s + 4 * q]);
        }
        waitcnt0();
#pragma unroll
        for (int it = 0; it < 12; it++) {
            int idx = it * NTHR + tid;
            *(float4*)&prev_sh[idx * 4] = tmp[it];
        }
        __syncthreads();

        // ---- stage B: BN1 stats per feature f=(c,p'); fold into Aw/bw -----
#pragma unroll
        for (int u = 0; u < 3; u++) {
            int f = tid + NTHR * u;               // 0..575
            float sum = 0.f;
#pragma unroll
            for (int bb = 0; bb < NB; bb++) sum += prev_sh[bb * 576 + f];
            float mu = sum * (1.f / NB);
            float var = 0.f;
#pragma unroll
            for (int bb = 0; bb < NB; bb++) {
                float d = prev_sh[bb * 576 + f] - mu; var = fmaf(d, d, var);
            }
            var *= (1.f / NB);
            float rs = rsqrtf(var + 1e-5f);
            float alpha = g1[f] * rs;
            float beta  = fmaf(-mu, alpha, b1[f]);
            float w = wgs[f % NP];
            Aw[f] = alpha * w;
            bw[f] = beta * w;
        }
        __syncthreads();
        if (tid < NC) {
            float acc = baggp;
#pragma unroll
            for (int q = 0; q < NP; q++) acc += bw[tid * NP + q];
            bconst[tid] = acc;
        }
        __syncthreads();

        // ---- stage C: agg(q=p) + gelu + xw -> res_sh ----------------------
#pragma unroll
        for (int u = 0; u < 4; u++) {
            int o = tid + NTHR * u;               // 0..767 = b'*48+c
            int c = o % NC;
            float acc = bconst[c];
            const float4* pv = (const float4*)&prev_sh[o * NP];
            const float4* aw = (const float4*)&Aw[c * NP];
#pragma unroll
            for (int q = 0; q < 3; q++) {
                float4 a4 = pv[q], w4 = aw[q];
                acc = fmaf(a4.x, w4.x, acc); acc = fmaf(a4.y, w4.y, acc);
                acc = fmaf(a4.z, w4.z, acc); acc = fmaf(a4.w, w4.w, acc);
            }
            res_sh[o] = gelu_exact(acc) + xn[o * NT + NP + NP * s + p];
        }
        __syncthreads();

        // ---- stage D: BN2 over b' ; t vector for our b --------------------
        if (tid < 32) ((float*)red)[tid] = 0.f;
        if (tid < NC) {
            int c = tid;
            float sum = 0.f;
#pragma unroll
            for (int bb = 0; bb < NB; bb++) sum += res_sh[bb * NC + c];
            float mu = sum * (1.f / NB);
            float var = 0.f;
#pragma unroll
            for (int bb = 0; bb < NB; bb++) {
                float d = res_sh[bb * NC + c] - mu; var = fmaf(d, d, var);
            }
            var *= (1.f / NB);
            float rs = rsqrtf(var + 1e-5f);
            tv[c] = (res_sh[b * NC + c] - mu) * rs * g2[c * NP + p] + b2[c * NP + p];
        }
        __syncthreads();

        // ---- stage E: edge MLP + top-3 + softmax + message ----------------
        {
            int j = tid % NC, rg = tid / NC;      // rg in 0..3
            float zj = tv[j];
            float zi[4], e[4];
#pragma unroll
            for (int k = 0; k < 4; k++) { zi[k] = tv[i0 + rg + 4 * k]; e[k] = 0.f; }

#pragma unroll 4
            for (int f = 0; f < NFF; f++) {
                float4 cf = coef[f];
                float base = fmaf(cf.y, zj, cf.z);
#pragma unroll
                for (int k = 0; k < 4; k++) {
                    float u = fmaf(cf.x, zi[k], base);
                    e[k] = fmaf(gelu_exact(u), cf.w, e[k]);
                }
            }
#pragma unroll
            for (int k = 0; k < 4; k++) erow[rg + 4 * k][j] = e[k];
            __syncthreads();

            if (tid < 16) {
                float m1 = -1e30f, m2 = -1e30f, m3 = -1e30f;
#pragma unroll 8
                for (int k = 0; k < NC; k++) {
                    float v = erow[tid][k];
                    float n1 = fmaxf(m1, v), r1 = fminf(m1, v);
                    float n2 = fmaxf(m2, r1), r2 = fminf(m2, r1);
                    float n3 = fmaxf(m3, r2);
                    m1 = n1; m2 = n2; m3 = n3;
                }
                rowm1[tid] = m1; rowm3[tid] = m3;
            }
            __syncthreads();

            float msg = fmaf(zj, wm, bmv);
#pragma unroll
            for (int k = 0; k < 4; k++) {
                int r = rg + 4 * k;
                float ek = e[k];
                if (ek >= rowm3[r]) {             // ~3 lanes per row
                    int rank = 0;
                    for (int kk = 0; kk < NC; kk++) {
                        float v = erow[r][kk];
                        rank += (v > ek) || (v == ek && kk < j);
                    }
                    if (rank < 3) {               // exact jax top_k tie-break
                        float w = __builtin_amdgcn_exp2f((ek - rowm1[r]) * 1.4426950408889634f);
                        atomicAdd(&red[r][0], w);
                        atomicAdd(&red[r][1], w * msg);
                    }
                }
            }
            __syncthreads();

            if (tid < 16) {
                int i = i0 + tid;
                float znew = red[tid][1] / red[tid][0];
                store_f_llc(&out[(b * NC + i) * NT + NP * (s + 1) + p],
                            res_sh[b * NC + i] + 0.5f * znew);     // ALPHA
            }
        }
        if (s < STEPS - 1) grid_barrier(bar, bar + 1);
    }
}

extern "C" void kernel_launch(void* const* d_in, const int* in_sizes, int n_in,
                              void* d_out, int out_size, void* d_ws, size_t ws_size,
                              hipStream_t stream)
{
    const float* x    = (const float*)d_in[0];
    const float* g0   = (const float*)d_in[1];
    const float* b0   = (const float*)d_in[2];
    const float* g1   = (const float*)d_in[3];
    const float* b1   = (const float*)d_in[4];
    const float* g2   = (const float*)d_in[5];
    const float* b2   = (const float*)d_in[6];
    const float* Wagg = (const float*)d_in[7];
    const float* bagg = (const float*)d_in[8];
    const float* W1   = (const float*)d_in[9];
    const float* bm1  = (const float*)d_in[10];
    const float* W2   = (const float*)d_in[11];
    // d_in[12] = bm2: uniform shift of e -> invariant under top-k & softmax
    const float* wmsg = (const float*)d_in[13];
    const float* bmsg = (const float*)d_in[14];
    float* out = (float*)d_out;

    float* xn = (float*)d_ws;                              // 73728 floats
    unsigned* bar = (unsigned*)((char*)d_ws + 73728 * 4);  // barrier flags

    hipMemsetAsync(bar, 0, 256, stream);   // zero barrier flags (capturable)
    fused_kernel<<<NBLK, NTHR, 0, stream>>>(x, g0, b0, g1, b1, g2, b2, Wagg,
                                            bagg, W1, bm1, W2, wmsg, bmsg,
                                            out, xn, bar);
}